// Round 8
// baseline (213.339 us; speedup 1.0000x reference)
//
#include <hip/hip_runtime.h>

// RGCN on MI355X. Algebra: mean-aggregate x per (relation,dst) FIRST (linearity
// of mean), then one fused [N,640]@[640,128] bf16 MFMA GEMM per layer
// (A = [x_row | 4 relation means], staged from two sources).
// R8: R7 with ext-vector type for nontemporal stores (HIP uint4 is a struct,
//     rejected by __builtin_nontemporal_store).

#define N_NODES 50000
#define N_EDGES 800000
#define N_REL 4
#define DIM 128
#define NPAD 50048              // 782 * 64 (GEMM BM=64 tiles)
#define RN (N_REL * N_NODES)    // 200000 buckets, key = dst*4 + et
#define CAP 32                  // bucket capacity (Poisson(4): P(>=32) ~ 1e-18)
#define NXCD 8
#define DRANGE 6250             // N_NODES / NXCD

// fused prep grid partition
#define HIST_G 391              // groups of 2048 edges: 391*2048 >= 800000
#define HIST_B (HIST_G * NXCD)  // 3128 blocks; block = (group, xcd-slot)
#define XCAST_B 3125            // 800000 8-elem chunks / 256
#define WPREP_B 640             // 2*128*640 / 256
#define PREP_B (HIST_B + XCAST_B + WPREP_B)

typedef __bf16 bf16x8 __attribute__((ext_vector_type(8)));
typedef float f32x4 __attribute__((ext_vector_type(4)));
typedef float f32x2 __attribute__((ext_vector_type(2)));
typedef unsigned int u32x4 __attribute__((ext_vector_type(4)));

__device__ __forceinline__ unsigned short f2bf(float f) {
    unsigned u = __builtin_bit_cast(unsigned, f);
    u += 0x7FFFu + ((u >> 16) & 1u);       // round-to-nearest-even
    return (unsigned short)(u >> 16);
}

// pack 2 f32 -> dword of 2 bf16 (RNE), elem0 in low 16
__device__ __forceinline__ unsigned cvt_pk_bf16(float lo, float hi) {
    unsigned r;
    asm("v_cvt_pk_bf16_f32 %0, %1, %2" : "=v"(r) : "v"(lo), "v"(hi));
    return r;
}

__device__ __forceinline__ void pk_add(f32x2& acc, f32x2 v) {
    asm("v_pk_add_f32 %0, %1, %0" : "+v"(acc) : "v"(v));
}

// accumulate one 16B chunk (8 bf16) into 4 packed f32 pairs
__device__ __forceinline__ void acc_row(f32x2* acc, uint4 d) {
#pragma unroll
    for (int k = 0; k < 4; k++) {
        unsigned dw = (&d.x)[k];
        f32x2 v;
        v[0] = __builtin_bit_cast(float, dw << 16);
        v[1] = __builtin_bit_cast(float, dw & 0xFFFF0000u);
        pk_add(acc[k], v);
    }
}

__device__ __forceinline__ void gload_lds16(const void* g, void* lds) {
    __builtin_amdgcn_global_load_lds(
        (const __attribute__((address_space(1))) void*)g,
        (__attribute__((address_space(3))) void*)lds, 16, 0, 0);
}

// ---------- fused prep: XCD-partitioned hist | xcast | wprep ----------
__global__ __launch_bounds__(256) void k_prep(const int* __restrict__ et,
                                              const int* __restrict__ dst,
                                              const int* __restrict__ src,
                                              int* __restrict__ cnt,
                                              unsigned short* __restrict__ elist,
                                              const float* __restrict__ X,
                                              unsigned short* __restrict__ Xb,
                                              const float* __restrict__ weights,
                                              const float* __restrict__ roots,
                                              unsigned short* __restrict__ wcatT) {
    const int blk = blockIdx.x, tid = threadIdx.x;
    if (blk < HIST_B) {
        // block = (group g, xcd slot x): handles edges [g*2048,(g+1)*2048)
        // with dst in [x*DRANGE,(x+1)*DRANGE). blockIdx%NXCD -> XCD round-robin,
        // so each bucket line is only ever dirtied by one XCD's L2.
        const int g = blk >> 3;
        const int x = blk & 7;
        const int lo = x * DRANGE, hi = lo + DRANGE;
        const int base = g * 2048;
#pragma unroll
        for (int j = 0; j < 8; j++) {
            int i = base + j * 256 + tid;
            if (i < N_EDGES) {
                int d = dst[i];
                if (d >= lo && d < hi) {
                    int rn = (d << 2) | et[i];
                    int rk = atomicAdd(&cnt[rn], 1);
                    if (rk < CAP) elist[(size_t)rn * CAP + rk] = (unsigned short)src[i];
                }
            }
        }
    } else if (blk < HIST_B + XCAST_B) {
        int i = (blk - HIST_B) * 256 + tid;          // one thread = 8 elems
        f32x4 a = *(const f32x4*)(X + (size_t)i * 8);
        f32x4 b = *(const f32x4*)(X + (size_t)i * 8 + 4);
        u32x4 o;
        o.x = cvt_pk_bf16(a[0], a[1]);
        o.y = cvt_pk_bf16(a[2], a[3]);
        o.z = cvt_pk_bf16(b[0], b[1]);
        o.w = cvt_pk_bf16(b[2], b[3]);
        *(u32x4*)(Xb + (size_t)i * 8) = o;
    } else {
        int idx = (blk - HIST_B - XCAST_B) * 256 + tid;
        int k = idx % 640;
        int n = (idx / 640) % 128;
        int l = idx / (640 * 128);
        float v;
        if (k < 128) {
            v = roots[(l * 128 + k) * 128 + n];
        } else {
            int r = (k - 128) >> 7;
            int kk = (k - 128) & 127;
            v = weights[((l * N_REL + r) * 128 + kk) * 128 + n];
        }
        wcatT[idx] = f2bf(v);
    }
}

// ---------- aggregate: wave = node, 16-lane group g = relation g; MLP-8 ----------
// xcat row = [mean_r0 | mean_r1 | mean_r2 | mean_r3]  (512 cols bf16)
__global__ __launch_bounds__(256) void k_agg(const unsigned short* __restrict__ Xb,
                                             const int* __restrict__ cnt,
                                             const unsigned short* __restrict__ elist,
                                             unsigned short* __restrict__ xcat) {
    int node = blockIdx.x * 4 + (threadIdx.x >> 6);
    int lane = threadIdx.x & 63;
    const int g = lane >> 4;     // relation
    const int t = lane & 15;     // lane-in-group: owns cols t*8..t*8+7 of that relation

    int bucket = (node << 2) | g;
    int c = cnt[bucket];
    c = (c > CAP) ? CAP : c;
    const unsigned short* ep = elist + ((size_t)bucket * CAP);
    uint4 e8 = *(const uint4*)ep;              // entries 0..7

    int i0 = e8.x & 0xFFFF, i1 = e8.x >> 16;
    int i2 = e8.y & 0xFFFF, i3 = e8.y >> 16;
    int i4 = e8.z & 0xFFFF, i5 = e8.z >> 16;
    int i6 = e8.w & 0xFFFF, i7 = e8.w >> 16;

    const size_t toff = (size_t)(t * 8);
    const uint4 z = {0, 0, 0, 0};
    f32x2 A0[4] = {}, A1[4] = {}, A2[4] = {}, A3[4] = {};
    f32x2 A4[4] = {}, A5[4] = {}, A6[4] = {}, A7[4] = {};

    // 8 gathers in flight
    {
        uint4 d0 = z, d1 = z, d2 = z, d3 = z, d4 = z, d5 = z, d6 = z, d7 = z;
        if (c > 0) d0 = *(const uint4*)(Xb + (size_t)i0 * DIM + toff);
        if (c > 1) d1 = *(const uint4*)(Xb + (size_t)i1 * DIM + toff);
        if (c > 2) d2 = *(const uint4*)(Xb + (size_t)i2 * DIM + toff);
        if (c > 3) d3 = *(const uint4*)(Xb + (size_t)i3 * DIM + toff);
        if (c > 4) d4 = *(const uint4*)(Xb + (size_t)i4 * DIM + toff);
        if (c > 5) d5 = *(const uint4*)(Xb + (size_t)i5 * DIM + toff);
        if (c > 6) d6 = *(const uint4*)(Xb + (size_t)i6 * DIM + toff);
        if (c > 7) d7 = *(const uint4*)(Xb + (size_t)i7 * DIM + toff);
        acc_row(A0, d0); acc_row(A1, d1); acc_row(A2, d2); acc_row(A3, d3);
        acc_row(A4, d4); acc_row(A5, d5); acc_row(A6, d6); acc_row(A7, d7);
    }
    // rare tail (P(c>8) ~ 2%)
    for (int j = 8; j < c; ++j) {
        int s = ep[j];
        uint4 d = *(const uint4*)(Xb + (size_t)s * DIM + toff);
        acc_row(A0, d);
    }
#pragma unroll
    for (int k = 0; k < 4; k++) {
        pk_add(A0[k], A1[k]);
        pk_add(A2[k], A3[k]);
        pk_add(A4[k], A5[k]);
        pk_add(A6[k], A7[k]);
        pk_add(A0[k], A2[k]);
        pk_add(A4[k], A6[k]);
        pk_add(A0[k], A4[k]);
    }

    float inv = 1.0f / fmaxf((float)c, 1.0f);
    u32x4 o;
    o.x = cvt_pk_bf16(A0[0][0] * inv, A0[0][1] * inv);
    o.y = cvt_pk_bf16(A0[1][0] * inv, A0[1][1] * inv);
    o.z = cvt_pk_bf16(A0[2][0] * inv, A0[2][1] * inv);
    o.w = cvt_pk_bf16(A0[3][0] * inv, A0[3][1] * inv);
    // nontemporal: don't let the 51 MB xcat stream evict the feature table
    __builtin_nontemporal_store(o, (u32x4*)(xcat + (size_t)node * 512 + g * 128 + t * 8));
}

// ---------- GEMM: Y[M,128] = [Xself | xcat][M,640](bf16) @ wcatT[128][640](bf16) ----------
// BM=64, BN=128, BK=64; 4 waves (2x2), each wave 32x64 out; 16x16x32 MFMA.
// A K-tiles 0..1 staged from Xself (stride 256B), 2..9 from xcat (stride 1024B).
__global__ __launch_bounds__(256) void k_gemm(const unsigned short* __restrict__ Xself,
                                              const unsigned short* __restrict__ Xagg,
                                              const unsigned short* __restrict__ Bt,
                                              const float* __restrict__ bias,
                                              void* __restrict__ Yv, int Mout,
                                              int relu, int obf16) {
    __shared__ unsigned short sA[64 * 64];    // [row][64 k] bf16, 16B-chunk XOR swizzled
    __shared__ unsigned short sB[128 * 64];   // [n][64 k]

    const int tid = threadIdx.x;
    const int lane = tid & 63;
    const int wid = tid >> 6;
    const int wm = wid >> 1, wn = wid & 1;
    const int m0 = blockIdx.x * 64;

    f32x4 acc[2][4] = {};

    const char* Bbase = (const char*)Bt;

    for (int kt = 0; kt < 10; ++kt) {
        const char* Asrc;
        size_t rstride;
        if (kt < 2) {
            Asrc = (const char*)Xself + (size_t)m0 * 256 + kt * 128;
            rstride = 256;
        } else {
            Asrc = (const char*)Xagg + (size_t)m0 * 1024 + (kt - 2) * 128;
            rstride = 1024;
        }
#pragma unroll
        for (int i = 0; i < 2; i++) {
            int chunk = i * 256 + tid;
            int row = chunk >> 3, cst = chunk & 7;
            int clog = cst ^ (row & 7);
            gload_lds16(Asrc + (size_t)row * rstride + clog * 16,
                        (char*)sA + (size_t)(chunk - lane) * 16);
        }
#pragma unroll
        for (int i = 0; i < 4; i++) {
            int chunk = i * 256 + tid;
            int row = chunk >> 3, cst = chunk & 7;
            int clog = cst ^ (row & 7);
            gload_lds16(Bbase + (size_t)row * 1280 + kt * 128 + clog * 16,
                        (char*)sB + (size_t)(chunk - lane) * 16);
        }
        __syncthreads();
#pragma unroll
        for (int ki = 0; ki < 2; ki++) {
            bf16x8 a[2], b[4];
#pragma unroll
            for (int mi = 0; mi < 2; mi++) {
                int row = wm * 32 + mi * 16 + (lane & 15);
                int c = ki * 4 + (lane >> 4);
                a[mi] = *(const bf16x8*)((const char*)sA + row * 128 + ((c ^ (row & 7)) << 4));
            }
#pragma unroll
            for (int ni = 0; ni < 4; ni++) {
                int row = wn * 64 + ni * 16 + (lane & 15);
                int c = ki * 4 + (lane >> 4);
                b[ni] = *(const bf16x8*)((const char*)sB + row * 128 + ((c ^ (row & 7)) << 4));
            }
#pragma unroll
            for (int mi = 0; mi < 2; mi++)
#pragma unroll
                for (int ni = 0; ni < 4; ni++)
                    acc[mi][ni] = __builtin_amdgcn_mfma_f32_16x16x32_bf16(a[mi], b[ni], acc[mi][ni], 0, 0, 0);
        }
        __syncthreads();
    }
#pragma unroll
    for (int mi = 0; mi < 2; mi++) {
#pragma unroll
        for (int ni = 0; ni < 4; ni++) {
            int col = wn * 64 + ni * 16 + (lane & 15);
            float bv = bias[col];
#pragma unroll
            for (int q = 0; q < 4; q++) {
                int row = m0 + wm * 32 + mi * 16 + (lane >> 4) * 4 + q;
                if (row < Mout) {
                    float v = acc[mi][ni][q] + bv;
                    if (relu) v = fmaxf(v, 0.f);
                    if (obf16) {
                        ((unsigned short*)Yv)[(size_t)row * DIM + col] = f2bf(v);
                    } else {
                        // final output, never re-read: nontemporal
                        __builtin_nontemporal_store(v, (float*)Yv + (size_t)row * DIM + col);
                    }
                }
            }
        }
    }
}

extern "C" void kernel_launch(void* const* d_in, const int* in_sizes, int n_in,
                              void* d_out, int out_size, void* d_ws, size_t ws_size,
                              hipStream_t stream) {
    const float* x = (const float*)d_in[0];
    const int* ei = (const int*)d_in[1];      // [2,E]: src = ei, dst = ei+E
    const int* et = (const int*)d_in[2];      // [E]
    const float* weights = (const float*)d_in[3];  // [L,R,D,D]
    const float* roots = (const float*)d_in[4];    // [L,D,D]
    const float* biases = (const float*)d_in[5];   // [L,D]
    float* out = (float*)d_out;

    const int* src = ei;
    const int* dst = ei + N_EDGES;

    // workspace layout (~91 MB)
    int* cnt = (int*)d_ws;                                        // 200064 ints
    unsigned short* elist = (unsigned short*)(cnt + 200064);      // RN*CAP u16 = 12.8 MB
    unsigned short* wcatT = elist + (size_t)RN * CAP;             // 2*128*640
    unsigned short* xcat = wcatT + 2 * 128 * 640;                 // NPAD*512 bf16 = 51.2 MB
    unsigned short* xb = xcat + (size_t)NPAD * 512;               // NPAD*128 bf16
    unsigned short* hb = xb + (size_t)NPAD * 128;                 // NPAD*128 bf16

    hipMemsetAsync(cnt, 0, (size_t)200064 * sizeof(int), stream);

    k_prep<<<PREP_B, 256, 0, stream>>>(et, dst, src, cnt, elist, x, xb, weights, roots, wcatT);

    // layer 0: xb -> hb (ReLU, bf16 out)
    k_agg<<<N_NODES / 4, 256, 0, stream>>>(xb, cnt, elist, xcat);
    k_gemm<<<NPAD / 64, 256, 0, stream>>>(xb, xcat, wcatT, biases, hb, N_NODES, 1, 1);
    // layer 1: hb -> out (no ReLU, fp32 out)
    k_agg<<<N_NODES / 4, 256, 0, stream>>>(hb, cnt, elist, xcat);
    k_gemm<<<NPAD / 64, 256, 0, stream>>>(hb, xcat, wcatT + 128 * 640, biases + DIM, out, N_NODES, 0, 0);
}